// Round 3
// baseline (2198.314 us; speedup 1.0000x reference)
//
#include <hip/hip_runtime.h>
#include <hip/hip_bf16.h>

// ---------------------------------------------------------------------------
// LPGCNHyperConvAblation. Compute fp32. Float inputs bf16 OR fp32 (runtime-
// detected per array, defensive); index inputs int32 OR int64 (detected).
// Output written fp32 (established round 2: harness buffers are fp32).
// ---------------------------------------------------------------------------

__device__ __forceinline__ float ldf(const void* p, int f32, long long i) {
    if (f32) return ((const float*)p)[i];
    unsigned v = ((unsigned)((const unsigned short*)p)[i]) << 16;
    return __uint_as_float(v);
}

__device__ __forceinline__ int ldi(const int* __restrict__ w, int i64, long long i, int lim) {
    int v = i64 ? w[2 * i] : w[i];
    return ((unsigned)v < (unsigned)lim) ? v : 0;
}

// --- dtype detection ---------------------------------------------------------
__global__ void detect_f32_k(const unsigned short* __restrict__ u, int nprobe, int* __restrict__ flag) {
    __shared__ int cnt;
    if (threadIdx.x == 0) cnt = 0;
    __syncthreads();
    int c = 0;
    for (int i = threadIdx.x; i < nprobe; i += blockDim.x) {
        unsigned e = (u[i] >> 7) & 0xFFu;
        if (e != 0u && (e < 90u || e > 160u)) c++;
    }
    atomicAdd(&cnt, c);
    __syncthreads();
    if (threadIdx.x == 0) flag[0] = (cnt * 8 > nprobe) ? 1 : 0;
}

__global__ void detect_i64_k(const int* __restrict__ w, int nprobe, int* __restrict__ flag) {
    __shared__ int nz;
    if (threadIdx.x == 0) nz = 0;
    __syncthreads();
    int c = 0;
    for (int i = threadIdx.x; i < nprobe; i += blockDim.x)
        if (w[2 * i + 1] != 0) c++;
    atomicAdd(&nz, c);
    __syncthreads();
    if (threadIdx.x == 0) flag[0] = (nz == 0) ? 1 : 0;
}

// --- small utility kernels ---------------------------------------------------
__global__ void fill_k(float* __restrict__ p, float v, int n) {
    int i = blockIdx.x * blockDim.x + threadIdx.x;
    if (i < n) p[i] = v;
}

__global__ void count_pairs_k(const int* __restrict__ hw, const int* __restrict__ f64,
                              float* __restrict__ Dn, float* __restrict__ Bh,
                              int P, int N, int HE) {
    int i = blockIdx.x * blockDim.x + threadIdx.x;
    if (i < P) {
        int g = f64[0];
        atomicAdd(&Dn[ldi(hw, g, i, N)], 1.f);
        atomicAdd(&Bh[ldi(hw, g, (long long)P + i, HE)], 1.f);
    }
}

__global__ void count_deg_k(const int* __restrict__ ew, const int* __restrict__ f64,
                            float* __restrict__ deg, int E, int N) {
    int i = blockIdx.x * blockDim.x + threadIdx.x;
    if (i < E) atomicAdd(&deg[ldi(ew, f64[0], (long long)E + i, N)], 1.f);
}

__global__ void rsqrt_k(float* __restrict__ p, int n) {
    int i = blockIdx.x * blockDim.x + threadIdx.x;
    if (i < n) p[i] = rsqrtf(fmaxf(p[i], 1.f));
}

// --- GEMM: C[NRxM] = A[NRxK] * B[KxM] (+C) (+bias) (relu) --------------------
template <bool BIAS, bool RELU, bool ACCUM>
__global__ void gemm_k(const void* __restrict__ A, const int* __restrict__ fA,
                       const void* __restrict__ B, const int* __restrict__ fB, long long bOff,
                       const void* __restrict__ bias, const int* __restrict__ fbias,
                       float* __restrict__ C, int NR, int K, int M) {
    const int af = fA ? fA[0] : 1;
    const int bf = fB[0];
    __shared__ float As[16][17];
    __shared__ float Bs[16][17];
    const int tx = threadIdx.x, ty = threadIdx.y;
    const int row = blockIdx.x * 16 + ty;
    const int col = blockIdx.y * 16 + tx;
    float acc = 0.f;
    for (int k0 = 0; k0 < K; k0 += 16) {
        int ak = k0 + tx;
        As[ty][tx] = (row < NR && ak < K) ? ldf(A, af, (long long)row * K + ak) : 0.f;
        int bk = k0 + ty;
        Bs[ty][tx] = (bk < K && col < M) ? ldf(B, bf, bOff + (long long)bk * M + col) : 0.f;
        __syncthreads();
#pragma unroll
        for (int kk = 0; kk < 16; ++kk) acc = fmaf(As[ty][kk], Bs[kk][tx], acc);
        __syncthreads();
    }
    if (row < NR && col < M) {
        long long o = (long long)row * M + col;
        if constexpr (ACCUM) acc += C[o];
        if constexpr (BIAS) acc += ldf(bias, fbias[0], col);
        if constexpr (RELU) acc = fmaxf(acc, 0.f);
        C[o] = acc;
    }
}

// --- hypergraph scatters -----------------------------------------------------
__global__ void scat_n2e_k(const float* __restrict__ xw, const int* __restrict__ hw,
                           const int* __restrict__ f64, float* __restrict__ ef,
                           int P, int N, int HE) {
    int t = blockIdx.x * blockDim.x + threadIdx.x;
    int p = t >> 6, f = t & 63;
    if (p < P) {
        int g = f64[0];
        int n = ldi(hw, g, p, N);
        int e = ldi(hw, g, (long long)P + p, HE);
        atomicAdd(&ef[(e << 6) + f], xw[(n << 6) + f]);
    }
}

__global__ void scale_e_k(float* __restrict__ ef, const float* __restrict__ Bh, int HE) {
    int t = blockIdx.x * blockDim.x + threadIdx.x;
    int e = t >> 6;
    if (e < HE) {
        float b = Bh[e];
        ef[t] *= (b >= 0.5f) ? (1.f / b) : 0.f;
    }
}

__global__ void scat_e2n_k(const float* __restrict__ ef, const int* __restrict__ hw,
                           const int* __restrict__ f64, float* __restrict__ acc,
                           int P, int N, int HE) {
    int t = blockIdx.x * blockDim.x + threadIdx.x;
    int p = t >> 6, f = t & 63;
    if (p < P) {
        int g = f64[0];
        int n = ldi(hw, g, p, N);
        int e = ldi(hw, g, (long long)P + p, HE);
        atomicAdd(&acc[(n << 6) + f], ef[(e << 6) + f]);
    }
}

template <bool RELU>
__global__ void hyper_post_k(float* __restrict__ h, const float* __restrict__ Dn,
                             const void* __restrict__ b, const int* __restrict__ fb, int n) {
    int t = blockIdx.x * blockDim.x + threadIdx.x;
    if (t < n) {
        int i = t >> 6, f = t & 63;
        float d = Dn[i];
        float inv = (d >= 0.5f) ? (1.f / d) : 0.f;
        float v = h[t] * inv + ldf(b, fb[0], f);
        if (RELU) v = fmaxf(v, 0.f);
        h[t] = v;
    }
}

// --- GCN ---------------------------------------------------------------------
template <int M>
__global__ void gcn_self_k(const float* __restrict__ xw, const float* __restrict__ dis,
                           float* __restrict__ g, int NR) {
    int t = blockIdx.x * blockDim.x + threadIdx.x;
    int i = t / M;
    if (i < NR) {
        float d = dis[i];
        g[t] = xw[t] * d * d;
    }
}

template <int M>
__global__ void gcn_edge_k(const float* __restrict__ xw, const int* __restrict__ ew,
                           const int* __restrict__ f64, const float* __restrict__ dis,
                           float* __restrict__ g, int E, int N) {
    int t = blockIdx.x * blockDim.x + threadIdx.x;
    int e = t / M, f = t - e * M;
    if (e < E) {
        int g64 = f64[0];
        int s = ldi(ew, g64, e, N);
        int d = ldi(ew, g64, (long long)E + e, N);
        atomicAdd(&g[d * M + f], xw[s * M + f] * dis[s] * dis[d]);
    }
}

template <int M, bool RELU>
__global__ void gcn_post_k(float* __restrict__ g, const void* __restrict__ b,
                           const int* __restrict__ fb, int n) {
    int t = blockIdx.x * blockDim.x + threadIdx.x;
    if (t < n) {
        int f = t % M;
        float v = g[t] + ldf(b, fb[0], f);
        if (RELU) v = fmaxf(v, 0.f);
        g[t] = v;
    }
}

static inline dim3 g1d(long long n, int b) { return dim3((unsigned)((n + b - 1) / b)); }
static inline int imin(int a, int b) { return a < b ? a : b; }

extern "C" void kernel_launch(void* const* d_in, const int* in_sizes, int n_in,
                              void* d_out, int out_size, void* d_ws, size_t ws_size,
                              hipStream_t stream) {
    const int N  = in_sizes[0] / 128;   // 100000
    const int E  = in_sizes[1] / 2;     // 1600000
    const int P  = in_sizes[2] / 2;     // 800000
    const int HE = 20000;

    const void* x    = d_in[0];
    const int*  ew   = (const int*)d_in[1];
    const int*  hw   = (const int*)d_in[2];
    const void* W_h1 = d_in[3];
    const void* b_h1 = d_in[4];
    const void* W_h2 = d_in[5];
    const void* b_h2 = d_in[6];
    const void* W_c1 = d_in[7];
    const void* b_c1 = d_in[8];
    const void* W_c2 = d_in[9];
    const void* b_c2 = d_in[10];
    const void* W_lp = d_in[11];
    const void* b_lp = d_in[12];

    float* ws  = (float*)d_ws;
    float* A0  = ws;                          // N*64
    float* A1  = A0 + (size_t)N * 64;         // N*64
    float* ef  = A1 + (size_t)N * 64;         // HE*64
    float* Dn  = ef + (size_t)HE * 64;        // N
    float* Bh  = Dn + N;                      // HE
    float* dis = Bh + HE;                     // N
    int*   FL  = (int*)(dis + N);             // 16 flags

    dim3 b256(256);
    dim3 gb(16, 16);
    dim3 d1(1);

    // ---- dtype detection ----
    const void* farr[11] = {x, W_h1, b_h1, W_h2, b_h2, W_c1, b_c1, W_c2, b_c2, W_lp, b_lp};
    const int   fsz[11]  = {in_sizes[0], in_sizes[3], in_sizes[4], in_sizes[5], in_sizes[6],
                            in_sizes[7], in_sizes[8], in_sizes[9], in_sizes[10], in_sizes[11],
                            in_sizes[12]};
    for (int i = 0; i < 11; ++i)
        detect_f32_k<<<d1, b256, 0, stream>>>((const unsigned short*)farr[i],
                                              imin(fsz[i], 2048), FL + i);
    detect_i64_k<<<d1, b256, 0, stream>>>(ew, imin(in_sizes[1] / 2, 1024), FL + 11);
    detect_i64_k<<<d1, b256, 0, stream>>>(hw, imin(in_sizes[2] / 2, 1024), FL + 12);
    const int* fX   = FL + 0;
    const int* fWh1 = FL + 1,  *fbh1 = FL + 2;
    const int* fWh2 = FL + 3,  *fbh2 = FL + 4;
    const int* fWc1 = FL + 5,  *fbc1 = FL + 6;
    const int* fWc2 = FL + 7,  *fbc2 = FL + 8;
    const int* fWlp = FL + 9,  *fblp = FL + 10;
    const int* fE64 = FL + 11, *fP64 = FL + 12;

    // ---- degrees ----
    hipMemsetAsync(Dn, 0, (size_t)(N + HE) * 4, stream);  // Dn, Bh
    fill_k<<<g1d(N, 256), b256, 0, stream>>>(dis, 1.f, N);
    count_pairs_k<<<g1d(P, 256), b256, 0, stream>>>(hw, fP64, Dn, Bh, P, N, HE);
    count_deg_k<<<g1d(E, 256), b256, 0, stream>>>(ew, fE64, dis, E, N);
    rsqrt_k<<<g1d(N, 256), b256, 0, stream>>>(dis, N);

    // ---- hyperconv 1 ----
    gemm_k<false, false, false><<<dim3((N + 15) / 16, 4), gb, 0, stream>>>(
        x, fX, W_h1, fWh1, 0, nullptr, nullptr, A0, N, 128, 64);
    hipMemsetAsync(ef, 0, (size_t)HE * 64 * 4, stream);
    scat_n2e_k<<<g1d((long long)P * 64, 256), b256, 0, stream>>>(A0, hw, fP64, ef, P, N, HE);
    scale_e_k<<<g1d((long long)HE * 64, 256), b256, 0, stream>>>(ef, Bh, HE);
    hipMemsetAsync(A1, 0, (size_t)N * 64 * 4, stream);
    scat_e2n_k<<<g1d((long long)P * 64, 256), b256, 0, stream>>>(ef, hw, fP64, A1, P, N, HE);
    hyper_post_k<true><<<g1d((long long)N * 64, 256), b256, 0, stream>>>(A1, Dn, b_h1, fbh1, N * 64);

    // ---- hyperconv 2 ----
    gemm_k<false, false, false><<<dim3((N + 15) / 16, 4), gb, 0, stream>>>(
        A1, nullptr, W_h2, fWh2, 0, nullptr, nullptr, A0, N, 64, 64);
    hipMemsetAsync(ef, 0, (size_t)HE * 64 * 4, stream);
    scat_n2e_k<<<g1d((long long)P * 64, 256), b256, 0, stream>>>(A0, hw, fP64, ef, P, N, HE);
    scale_e_k<<<g1d((long long)HE * 64, 256), b256, 0, stream>>>(ef, Bh, HE);
    hipMemsetAsync(A1, 0, (size_t)N * 64 * 4, stream);
    scat_e2n_k<<<g1d((long long)P * 64, 256), b256, 0, stream>>>(ef, hw, fP64, A1, P, N, HE);
    hyper_post_k<false><<<g1d((long long)N * 64, 256), b256, 0, stream>>>(A1, Dn, b_h2, fbh2, N * 64);
    // A1 = x_hyper

    // ---- gcn 1: [x, x_hyper] @ W_c1 ----
    gemm_k<false, false, false><<<dim3((N + 15) / 16, 4), gb, 0, stream>>>(
        x, fX, W_c1, fWc1, 0, nullptr, nullptr, A0, N, 128, 64);
    gemm_k<false, false, true><<<dim3((N + 15) / 16, 4), gb, 0, stream>>>(
        A1, nullptr, W_c1, fWc1, (long long)128 * 64, nullptr, nullptr, A0, N, 64, 64);
    gcn_self_k<64><<<g1d((long long)N * 64, 256), b256, 0, stream>>>(A0, dis, A1, N);
    gcn_edge_k<64><<<g1d((long long)E * 64, 256), b256, 0, stream>>>(A0, ew, fE64, dis, A1, E, N);
    gcn_post_k<64, true><<<g1d((long long)N * 64, 256), b256, 0, stream>>>(A1, b_c1, fbc1, N * 64);

    // ---- gcn 2 ----
    gemm_k<false, false, false><<<dim3((N + 15) / 16, 3), gb, 0, stream>>>(
        A1, nullptr, W_c2, fWc2, 0, nullptr, nullptr, A0, N, 64, 40);
    gcn_self_k<40><<<g1d((long long)N * 40, 256), b256, 0, stream>>>(A0, dis, A1, N);
    gcn_edge_k<40><<<g1d((long long)E * 40, 256), b256, 0, stream>>>(A0, ew, fE64, dis, A1, E, N);
    gcn_post_k<40, false><<<g1d((long long)N * 40, 256), b256, 0, stream>>>(A1, b_c2, fbc2, N * 40);

    // ---- final linear -> fp32 out ----
    gemm_k<true, false, false><<<dim3((N + 15) / 16, 3), gb, 0, stream>>>(
        A1, nullptr, W_lp, fWlp, 0, b_lp, fblp, (float*)d_out, N, 40, 40);
}

// Round 4
// 1073.583 us; speedup vs baseline: 2.0476x; 2.0476x over previous
//
#include <hip/hip_runtime.h>
#include <hip/hip_bf16.h>

// ---------------------------------------------------------------------------
// LPGCNHyperConvAblation, round 4: CSR-gather everywhere (no feature atomics),
// register-blocked 64x64 GEMM. Compute fp32; inputs fp32 (runtime dtype
// detection kept as insurance); output fp32.
// ---------------------------------------------------------------------------

__device__ __forceinline__ float ldf(const void* p, int f32, long long i) {
    if (f32) return ((const float*)p)[i];
    unsigned v = ((unsigned)((const unsigned short*)p)[i]) << 16;
    return __uint_as_float(v);
}

__device__ __forceinline__ int ldi(const int* __restrict__ w, int i64, long long i, int lim) {
    int v = i64 ? w[2 * i] : w[i];
    return ((unsigned)v < (unsigned)lim) ? v : 0;
}

// --- dtype detection ---------------------------------------------------------
struct FPtrs { const void* p[11]; int n[11]; };

__global__ void detect_all_f32_k(FPtrs fp, int* __restrict__ flags) {
    const unsigned short* u = (const unsigned short*)fp.p[blockIdx.x];
    int nprobe = fp.n[blockIdx.x]; if (nprobe > 2048) nprobe = 2048;
    __shared__ int cnt;
    if (threadIdx.x == 0) cnt = 0;
    __syncthreads();
    int c = 0;
    for (int i = threadIdx.x; i < nprobe; i += blockDim.x) {
        unsigned e = (u[i] >> 7) & 0xFFu;
        if (e != 0u && (e < 90u || e > 160u)) c++;
    }
    atomicAdd(&cnt, c);
    __syncthreads();
    if (threadIdx.x == 0) flags[blockIdx.x] = (cnt * 8 > nprobe) ? 1 : 0;
}

__global__ void detect_i64_k(const int* __restrict__ w, int nprobe, int* __restrict__ flag) {
    __shared__ int nz;
    if (threadIdx.x == 0) nz = 0;
    __syncthreads();
    int c = 0;
    for (int i = threadIdx.x; i < nprobe; i += blockDim.x)
        if (w[2 * i + 1] != 0) c++;
    atomicAdd(&nz, c);
    __syncthreads();
    if (threadIdx.x == 0) flag[0] = (nz == 0) ? 1 : 0;
}

// --- counting ----------------------------------------------------------------
__global__ void count_edge_k(const int* __restrict__ ew, const int* __restrict__ f64,
                             int* __restrict__ cnt, int E, int N) {
    int i = blockIdx.x * blockDim.x + threadIdx.x;
    if (i < E) atomicAdd(&cnt[ldi(ew, f64[0], (long long)E + i, N)], 1);
}

__global__ void count_pair_k(const int* __restrict__ hw, const int* __restrict__ f64,
                             int* __restrict__ cntN, int* __restrict__ cntH,
                             int P, int N, int HE) {
    int i = blockIdx.x * blockDim.x + threadIdx.x;
    if (i < P) {
        int g = f64[0];
        atomicAdd(&cntN[ldi(hw, g, i, N)], 1);
        atomicAdd(&cntH[ldi(hw, g, (long long)P + i, HE)], 1);
    }
}

// --- exclusive scan (2048 elems/block, 2-level) ------------------------------
#define SCAN_CHUNK 2048

__global__ void scan_part_k(const int* __restrict__ in, int* __restrict__ out,
                            int* __restrict__ bsum, int n) {
    __shared__ int sh[256];
    int b = blockIdx.x, t = threadIdx.x;
    int base = b * SCAN_CHUNK + t * 8;
    int v[8];
    int sum = 0;
#pragma unroll
    for (int j = 0; j < 8; j++) { int idx = base + j; v[j] = (idx < n) ? in[idx] : 0; sum += v[j]; }
    sh[t] = sum;
    __syncthreads();
    for (int o = 1; o < 256; o <<= 1) {
        int y = (t >= o) ? sh[t - o] : 0;
        __syncthreads();
        sh[t] += y;
        __syncthreads();
    }
    int run = sh[t] - sum;   // exclusive prefix within block
    if (t == 255) bsum[b] = sh[255];
#pragma unroll
    for (int j = 0; j < 8; j++) { int idx = base + j; if (idx < n) out[idx] = run; run += v[j]; }
}

__global__ void scan_top_k(int* __restrict__ bsum, int nb) {
    if (threadIdx.x == 0) {
        int acc = 0;
        for (int i = 0; i < nb; i++) { int v = bsum[i]; bsum[i] = acc; acc += v; }
    }
}

__global__ void scan_add_k(int* __restrict__ out, const int* __restrict__ bsum, int n) {
    int i = blockIdx.x * blockDim.x + threadIdx.x;
    if (i < n) out[i] += bsum[i / SCAN_CHUNK];
}

// --- CSR fill ----------------------------------------------------------------
__global__ void build_edge_k(const int* __restrict__ ew, const int* __restrict__ f64,
                             const int* __restrict__ off, int* __restrict__ cur,
                             int* __restrict__ lst, int E, int N) {
    int i = blockIdx.x * blockDim.x + threadIdx.x;
    if (i < E) {
        int g = f64[0];
        int s = ldi(ew, g, i, N);
        int d = ldi(ew, g, (long long)E + i, N);
        int slot = atomicAdd(&cur[d], 1);
        lst[off[d] + slot] = s;
    }
}

__global__ void build_pair_k(const int* __restrict__ hw, const int* __restrict__ f64,
                             const int* __restrict__ offN, int* __restrict__ curN, int* __restrict__ lstN,
                             const int* __restrict__ offH, int* __restrict__ curH, int* __restrict__ lstH,
                             int P, int N, int HE) {
    int i = blockIdx.x * blockDim.x + threadIdx.x;
    if (i < P) {
        int g = f64[0];
        int nd = ldi(hw, g, i, N);
        int he = ldi(hw, g, (long long)P + i, HE);
        int s1 = atomicAdd(&curN[nd], 1); lstN[offN[nd] + s1] = he;
        int s2 = atomicAdd(&curH[he], 1); lstH[offH[he] + s2] = nd;
    }
}

// --- norm factors ------------------------------------------------------------
__global__ void dis_k(const int* __restrict__ cnt, float* __restrict__ dis, int n) {
    int i = blockIdx.x * blockDim.x + threadIdx.x;
    if (i < n) dis[i] = rsqrtf((float)(cnt[i] + 1));   // +1 self loop
}

__global__ void dinv_k(const int* __restrict__ cnt, float* __restrict__ dinv, int n) {
    int i = blockIdx.x * blockDim.x + threadIdx.x;
    if (i < n) { int c = cnt[i]; dinv[i] = (c > 0) ? (1.f / (float)c) : 0.f; }
}

// --- gathers (wave per destination row, lane = feature) ----------------------
// node -> hyperedge: ef[e] = Binv[e] * sum_{n in e} xw[n]
__global__ void gat_n2e_k(const float* __restrict__ xw, const int* __restrict__ off,
                          const int* __restrict__ cnt, const int* __restrict__ lst,
                          const float* __restrict__ Binv, float* __restrict__ ef, int HE) {
    int w = (blockIdx.x * blockDim.x + threadIdx.x) >> 6;
    int lane = threadIdx.x & 63;
    if (w < HE) {
        int o = off[w], c = cnt[w];
        float acc = 0.f;
#pragma unroll 4
        for (int j = 0; j < c; j++) {
            int nd = lst[o + j];
            acc += xw[((long long)nd << 6) + lane];
        }
        ef[((long long)w << 6) + lane] = acc * Binv[w];
    }
}

// hyperedge -> node + bias (+relu): out[n] = Dinv[n]*sum ef[e] + b
template <bool RELU>
__global__ void gat_e2n_k(const float* __restrict__ ef, const int* __restrict__ off,
                          const int* __restrict__ cnt, const int* __restrict__ lst,
                          const float* __restrict__ Dinv, const void* __restrict__ bias,
                          const int* __restrict__ fb, float* __restrict__ out, int N) {
    int w = (blockIdx.x * blockDim.x + threadIdx.x) >> 6;
    int lane = threadIdx.x & 63;
    if (w < N) {
        int o = off[w], c = cnt[w];
        float acc = 0.f;
#pragma unroll 4
        for (int j = 0; j < c; j++) {
            int he = lst[o + j];
            acc += ef[((long long)he << 6) + lane];
        }
        float v = acc * Dinv[w] + ldf(bias, fb[0], lane);
        if (RELU) v = fmaxf(v, 0.f);
        out[((long long)w << 6) + lane] = v;
    }
}

// GCN aggregation, fused self-loop + norm + bias (+relu):
// out[d] = dis[d]*( xw[d]*dis[d] + sum_s xw[s]*dis[s] ) + b
template <int M, bool RELU>
__global__ void gcn_gat_k(const float* __restrict__ xw, const int* __restrict__ off,
                          const int* __restrict__ cnt, const int* __restrict__ lst,
                          const float* __restrict__ dis, const void* __restrict__ bias,
                          const int* __restrict__ fb, float* __restrict__ out, int N) {
    int w = (blockIdx.x * blockDim.x + threadIdx.x) >> 6;
    int lane = threadIdx.x & 63;
    if (w < N && lane < M) {
        float dd = dis[w];
        int o = off[w], c = cnt[w];
        float acc = xw[(long long)w * M + lane] * dd;   // self loop
#pragma unroll 4
        for (int j = 0; j < c; j++) {
            int s = lst[o + j];
            acc += xw[(long long)s * M + lane] * dis[s];
        }
        float v = acc * dd + ldf(bias, fb[0], lane);
        if (RELU) v = fmaxf(v, 0.f);
        out[(long long)w * M + lane] = v;
    }
}

// --- GEMM: 64x64 tile, 256 threads, 4x4 per-thread micro-tile ----------------
template <bool BIAS, bool RELU, bool ACCUM>
__global__ __launch_bounds__(256)
void gemm64_k(const void* __restrict__ A, const int* __restrict__ fA,
              const void* __restrict__ B, const int* __restrict__ fB, long long bOff,
              const void* __restrict__ bias, const int* __restrict__ fb,
              float* __restrict__ C, int NR, int K, int M) {
    const int af = fA ? fA[0] : 1;
    const int bf = fB[0];
    __shared__ float As[16][65];   // [k][m]
    __shared__ float Bs[16][65];   // [k][n]
    const int t = threadIdx.x;
    const int tx = t & 15, ty = t >> 4;
    const long long m0 = (long long)blockIdx.x * 64;
    float c[4][4] = {};
    for (int k0 = 0; k0 < K; k0 += 16) {
        {
            int row = t >> 2;
            int kk = (t & 3) * 4;
            long long r = m0 + row;
#pragma unroll
            for (int j = 0; j < 4; j++) {
                int k = k0 + kk + j;
                As[kk + j][row] = (r < NR && k < K) ? ldf(A, af, r * K + k) : 0.f;
            }
        }
        {
            int krow = t >> 4;
            int nn = (t & 15) * 4;
            int k = k0 + krow;
#pragma unroll
            for (int j = 0; j < 4; j++) {
                int n = nn + j;
                Bs[krow][nn + j] = (k < K && n < M) ? ldf(B, bf, bOff + (long long)k * M + n) : 0.f;
            }
        }
        __syncthreads();
#pragma unroll
        for (int k = 0; k < 16; k++) {
            float a[4], b[4];
#pragma unroll
            for (int i = 0; i < 4; i++) a[i] = As[k][ty * 4 + i];
#pragma unroll
            for (int j = 0; j < 4; j++) b[j] = Bs[k][tx * 4 + j];
#pragma unroll
            for (int i = 0; i < 4; i++)
#pragma unroll
                for (int j = 0; j < 4; j++) c[i][j] = fmaf(a[i], b[j], c[i][j]);
        }
        __syncthreads();
    }
#pragma unroll
    for (int i = 0; i < 4; i++) {
        long long r = m0 + ty * 4 + i;
        if (r < NR) {
#pragma unroll
            for (int j = 0; j < 4; j++) {
                int n = tx * 4 + j;
                if (n < M) {
                    long long o = r * M + n;
                    float v = c[i][j];
                    if constexpr (ACCUM) v += C[o];
                    if constexpr (BIAS) v += ldf(bias, fb[0], n);
                    if constexpr (RELU) v = fmaxf(v, 0.f);
                    C[o] = v;
                }
            }
        }
    }
}

static inline dim3 g1d(long long n, int b) { return dim3((unsigned)((n + b - 1) / b)); }
static inline int imin(int a, int b) { return a < b ? a : b; }

extern "C" void kernel_launch(void* const* d_in, const int* in_sizes, int n_in,
                              void* d_out, int out_size, void* d_ws, size_t ws_size,
                              hipStream_t stream) {
    const int N  = in_sizes[0] / 128;   // 100000
    const int E  = in_sizes[1] / 2;     // 1600000
    const int P  = in_sizes[2] / 2;     // 800000
    const int HE = 20000;

    const void* x    = d_in[0];
    const int*  ew   = (const int*)d_in[1];
    const int*  hw   = (const int*)d_in[2];
    const void* W_h1 = d_in[3];
    const void* b_h1 = d_in[4];
    const void* W_h2 = d_in[5];
    const void* b_h2 = d_in[6];
    const void* W_c1 = d_in[7];
    const void* b_c1 = d_in[8];
    const void* W_c2 = d_in[9];
    const void* b_c2 = d_in[10];
    const void* W_lp = d_in[11];
    const void* b_lp = d_in[12];

    // ---- workspace layout ----
    char* wp = (char*)d_ws;
    auto allocF = [&](size_t n) { float* p = (float*)wp; wp += n * 4; return p; };
    auto allocI = [&](size_t n) { int* p = (int*)wp; wp += n * 4; return p; };
    float* A0   = allocF((size_t)N * 64);
    float* A1   = allocF((size_t)N * 64);
    float* ef   = allocF((size_t)HE * 64);
    float* dis  = allocF(N);
    float* Dinv = allocF(N);
    float* Binv = allocF(HE);
    int* ecnt  = allocI(N);    // contiguous cnt block: ecnt,pcntN,pcntH
    int* pcntN = allocI(N);
    int* pcntH = allocI(HE);
    int* ecur  = allocI(N);    // contiguous cur block
    int* pcurN = allocI(N);
    int* pcurH = allocI(HE);
    int* eoff  = allocI(N);
    int* poffN = allocI(N);
    int* poffH = allocI(HE);
    int* esrc  = allocI(E);
    int* pheL  = allocI(P);    // per-node sorted: hyperedge ids
    int* pniL  = allocI(P);    // per-he sorted: node ids
    int* bsum  = allocI(2048);
    int* FL    = allocI(16);

    dim3 b256(256), d1(1);

    // ---- dtype detection ----
    FPtrs fp;
    const void* farr[11] = {x, W_h1, b_h1, W_h2, b_h2, W_c1, b_c1, W_c2, b_c2, W_lp, b_lp};
    const int   fsz[11]  = {in_sizes[0], in_sizes[3], in_sizes[4], in_sizes[5], in_sizes[6],
                            in_sizes[7], in_sizes[8], in_sizes[9], in_sizes[10], in_sizes[11],
                            in_sizes[12]};
    for (int i = 0; i < 11; ++i) { fp.p[i] = farr[i]; fp.n[i] = fsz[i]; }
    detect_all_f32_k<<<dim3(11), b256, 0, stream>>>(fp, FL);
    detect_i64_k<<<d1, b256, 0, stream>>>(ew, imin(E, 1024), FL + 11);
    detect_i64_k<<<d1, b256, 0, stream>>>(hw, imin(P, 1024), FL + 12);
    const int* fX   = FL + 0;
    const int* fWh1 = FL + 1,  *fbh1 = FL + 2;
    const int* fWh2 = FL + 3,  *fbh2 = FL + 4;
    const int* fWc1 = FL + 5,  *fbc1 = FL + 6;
    const int* fWc2 = FL + 7,  *fbc2 = FL + 8;
    const int* fWlp = FL + 9,  *fblp = FL + 10;
    const int* fE64 = FL + 11, *fP64 = FL + 12;

    // ---- degree counts ----
    hipMemsetAsync(ecnt, 0, (size_t)(2 * N + HE) * 4, stream);
    count_edge_k<<<g1d(E, 256), b256, 0, stream>>>(ew, fE64, ecnt, E, N);
    count_pair_k<<<g1d(P, 256), b256, 0, stream>>>(hw, fP64, pcntN, pcntH, P, N, HE);

    // ---- exclusive scans ----
    auto scan = [&](const int* in, int* out, int n) {
        int nb = (n + SCAN_CHUNK - 1) / SCAN_CHUNK;
        scan_part_k<<<dim3(nb), b256, 0, stream>>>(in, out, bsum, n);
        scan_top_k<<<d1, dim3(64), 0, stream>>>(bsum, nb);
        scan_add_k<<<g1d(n, 256), b256, 0, stream>>>(out, bsum, n);
    };
    scan(ecnt, eoff, N);
    scan(pcntN, poffN, N);
    scan(pcntH, poffH, HE);

    // ---- CSR fill ----
    hipMemsetAsync(ecur, 0, (size_t)(2 * N + HE) * 4, stream);
    build_edge_k<<<g1d(E, 256), b256, 0, stream>>>(ew, fE64, eoff, ecur, esrc, E, N);
    build_pair_k<<<g1d(P, 256), b256, 0, stream>>>(hw, fP64, poffN, pcurN, pheL,
                                                   poffH, pcurH, pniL, P, N, HE);

    // ---- norm factors ----
    dis_k<<<g1d(N, 256), b256, 0, stream>>>(ecnt, dis, N);
    dinv_k<<<g1d(N, 256), b256, 0, stream>>>(pcntN, Dinv, N);
    dinv_k<<<g1d(HE, 256), b256, 0, stream>>>(pcntH, Binv, HE);

    const dim3 gemmGrid((N + 63) / 64);
    const dim3 gatN(g1d((long long)N * 64, 256));    // wave per node
    const dim3 gatH(g1d((long long)HE * 64, 256));   // wave per hyperedge

    // ---- hyperconv 1 ----
    gemm64_k<false, false, false><<<gemmGrid, b256, 0, stream>>>(
        x, fX, W_h1, fWh1, 0, nullptr, nullptr, A0, N, 128, 64);
    gat_n2e_k<<<gatH, b256, 0, stream>>>(A0, poffH, pcntH, pniL, Binv, ef, HE);
    gat_e2n_k<true><<<gatN, b256, 0, stream>>>(ef, poffN, pcntN, pheL, Dinv, b_h1, fbh1, A1, N);

    // ---- hyperconv 2 ----
    gemm64_k<false, false, false><<<gemmGrid, b256, 0, stream>>>(
        A1, nullptr, W_h2, fWh2, 0, nullptr, nullptr, A0, N, 64, 64);
    gat_n2e_k<<<gatH, b256, 0, stream>>>(A0, poffH, pcntH, pniL, Binv, ef, HE);
    gat_e2n_k<false><<<gatN, b256, 0, stream>>>(ef, poffN, pcntN, pheL, Dinv, b_h2, fbh2, A1, N);
    // A1 = x_hyper

    // ---- gcn 1: [x, x_hyper] @ W_c1, then aggregate ----
    gemm64_k<false, false, false><<<gemmGrid, b256, 0, stream>>>(
        x, fX, W_c1, fWc1, 0, nullptr, nullptr, A0, N, 128, 64);
    gemm64_k<false, false, true><<<gemmGrid, b256, 0, stream>>>(
        A1, nullptr, W_c1, fWc1, (long long)128 * 64, nullptr, nullptr, A0, N, 64, 64);
    gcn_gat_k<64, true><<<gatN, b256, 0, stream>>>(A0, eoff, ecnt, esrc, dis, b_c1, fbc1, A1, N);

    // ---- gcn 2 ----
    gemm64_k<false, false, false><<<gemmGrid, b256, 0, stream>>>(
        A1, nullptr, W_c2, fWc2, 0, nullptr, nullptr, A0, N, 64, 40);
    gcn_gat_k<40, false><<<gatN, b256, 0, stream>>>(A0, eoff, ecnt, esrc, dis, b_c2, fbc2, A1, N);

    // ---- final linear -> fp32 out ----
    gemm64_k<true, false, false><<<gemmGrid, b256, 0, stream>>>(
        A1, nullptr, W_lp, fWlp, 0, b_lp, fblp, (float*)d_out, N, 40, 40);
}